// Round 8
// baseline (215.030 us; speedup 1.0000x reference)
//
#include <hip/hip_runtime.h>
#include <hip/hip_bf16.h>

#define Bb 2
#define Tt 2048
#define Cc 1024
#define Hh 16
#define HD 64
// 1/sqrt(64) * log2(e), folded into q at QKV epilogue so attn exp2 needs no mul
#define QS 0.18033688f

typedef __attribute__((ext_vector_type(8))) short bf16x8;
typedef __attribute__((ext_vector_type(4))) short bf16x4;
typedef __attribute__((ext_vector_type(4))) float f32x4;
typedef __attribute__((ext_vector_type(2))) unsigned int u32x2;

__device__ inline short f2b(float f) {
    unsigned int u = __builtin_bit_cast(unsigned int, f);
    unsigned int r = (u + 0x7FFFu + ((u >> 16) & 1u)) >> 16;
    return (short)(unsigned short)r;
}

// async global->LDS, 16B per lane; dst must be wave-uniform base + lane*16
__device__ inline void gl16(const void* g, void* l) {
    __builtin_amdgcn_global_load_lds(
        (const __attribute__((address_space(1))) void*)g,
        (__attribute__((address_space(3))) void*)l, 16, 0, 0);
}

// ---------------------------------------------------------------------------
// Fused pre-pass (single launch):
//   blocks [0,2048):      x fp32 -> bf16
//   blocks [2048,2816):   w_attn [1024,3072] -> wAT [3072][1024] bf16
//   blocks [2816,3072):   w_proj [1024,1024] -> wPT [1024][1024] bf16
// ---------------------------------------------------------------------------
__global__ __launch_bounds__(256) void prep_kernel(
    const float* __restrict__ x, short* __restrict__ xbf,
    const float* __restrict__ wA, short* __restrict__ wAT,
    const float* __restrict__ wP, short* __restrict__ wPT)
{
    const int bx = blockIdx.x, tid = threadIdx.x;
    if (bx < 2048) {
        int i = (bx * 256 + tid) * 8;
        float4 a = *(const float4*)(x + i);
        float4 b = *(const float4*)(x + i + 4);
        bf16x8 v;
        v[0] = f2b(a.x); v[1] = f2b(a.y); v[2] = f2b(a.z); v[3] = f2b(a.w);
        v[4] = f2b(b.x); v[5] = f2b(b.y); v[6] = f2b(b.z); v[7] = f2b(b.w);
        *(bf16x8*)(xbf + i) = v;
        return;
    }
    const float* W; short* WT; int N, t;
    if (bx < 2816) { t = bx - 2048; W = wA; WT = wAT; N = 3072; }
    else           { t = bx - 2816; W = wP; WT = wPT; N = 1024; }
    const int K = 1024;
    int k0 = (t & 15) * 64, n0 = (t >> 4) * 64;
    int nl = tid & 63, kg = tid >> 6;
    int n = n0 + nl;
    short v[16];
#pragma unroll
    for (int i = 0; i < 16; i++)
        v[i] = f2b(W[(size_t)(k0 + kg * 16 + i) * N + n]);
    short* dst = WT + (size_t)n * K + k0 + kg * 16;
    *(bf16x8*)dst = *(bf16x8*)&v[0];
    *(bf16x8*)(dst + 8) = *(bf16x8*)&v[8];
}

// ---------------------------------------------------------------------------
// QKV GEMM: 128x128 tile, BK=64 (16 barriers), XOR-swizzled LDS slots so both
// staging (gl16, lane-contiguous dst) and fragment b128 reads are
// conflict-free. A bf16 row-major, Bt pre-transposed [N][K].
// Epilogue scatters q(*QS),k -> [B,H,T,HD], v -> [B,H,HD,T].
// ---------------------------------------------------------------------------
__global__ __launch_bounds__(256) void gemm_qkv(
    const short* __restrict__ A, const short* __restrict__ Bt,
    const float* __restrict__ bias,
    short* __restrict__ qw, short* __restrict__ kw, short* __restrict__ vTw,
    int M, int N, int K)
{
    __shared__ __attribute__((aligned(16))) short As[128 * 64];
    __shared__ __attribute__((aligned(16))) short Bs[128 * 64];

    const int tid  = threadIdx.x;
    const int wave = tid >> 6, lane = tid & 63;
    const int quad = lane >> 4, lr = lane & 15;
    const int wm = wave >> 1, wn = wave & 1;
    const int m0 = blockIdx.y * 128, n0 = blockIdx.x * 128;

    // staging geometry: id in [0,1024), row=id>>3, slot=id&7 stores col-chunk
    // (id&7)^(row&7)
    int srow[4], scol[4];
#pragma unroll
    for (int i = 0; i < 4; i++) {
        int id = i * 256 + tid;
        srow[i] = id >> 3;
        scol[i] = ((id & 7) ^ (srow[i] & 7)) << 3;
    }

    f32x4 acc[4][4];
    const f32x4 zf = {0.f, 0.f, 0.f, 0.f};
#pragma unroll
    for (int mi = 0; mi < 4; mi++)
#pragma unroll
        for (int ni = 0; ni < 4; ni++) acc[mi][ni] = zf;

    for (int k0 = 0; k0 < K; k0 += 64) {
        __syncthreads();
#pragma unroll
        for (int i = 0; i < 4; i++) {
            gl16(A + (size_t)(m0 + srow[i]) * K + k0 + scol[i],
                 &As[(i * 256 + tid) * 8]);
            gl16(Bt + (size_t)(n0 + srow[i]) * K + k0 + scol[i],
                 &Bs[(i * 256 + tid) * 8]);
        }
        __syncthreads();

#pragma unroll
        for (int ks = 0; ks < 2; ks++) {
            bf16x8 af[4], bf[4];
#pragma unroll
            for (int mi = 0; mi < 4; mi++) {
                int row = wm * 64 + mi * 16 + lr;
                af[mi] = *(bf16x8*)&As[(row * 8 + ((ks * 4 + quad) ^ (lr & 7))) * 8];
            }
#pragma unroll
            for (int ni = 0; ni < 4; ni++) {
                int row = wn * 64 + ni * 16 + lr;
                bf[ni] = *(bf16x8*)&Bs[(row * 8 + ((ks * 4 + quad) ^ (lr & 7))) * 8];
            }
#pragma unroll
            for (int mi = 0; mi < 4; mi++)
#pragma unroll
                for (int ni = 0; ni < 4; ni++)
                    acc[mi][ni] = __builtin_amdgcn_mfma_f32_16x16x32_bf16(
                        af[mi], bf[ni], acc[mi][ni], 0, 0, 0);
        }
    }

#pragma unroll
    for (int mi = 0; mi < 4; mi++) {
#pragma unroll
        for (int ni = 0; ni < 4; ni++) {
            int c = n0 + wn * 64 + ni * 16 + lr;
            float bv = bias[c];
#pragma unroll
            for (int r = 0; r < 4; r++) {
                int rg = m0 + wm * 64 + mi * 16 + quad * 4 + r;
                float val = acc[mi][ni][r] + bv;
                int which = c >> 10, cc = c & 1023;
                int h = cc >> 6, d = cc & 63;
                int b = rg >> 11, t = rg & 2047;
                size_t bh = (size_t)b * Hh + h;
                if (which == 0)      qw[(bh * Tt + t) * HD + d] = f2b(val * QS);
                else if (which == 1) kw[(bh * Tt + t) * HD + d] = f2b(val);
                else                 vTw[(bh * HD + d) * Tt + t] = f2b(val);
            }
        }
    }
}

// ---------------------------------------------------------------------------
// Proj GEMM: 64x128 tile (2 blocks/CU), A head-gather [B,H,T,HD], fp32 out.
// ---------------------------------------------------------------------------
__global__ __launch_bounds__(256) void gemm_proj(
    const short* __restrict__ A, const short* __restrict__ Bt,
    const float* __restrict__ bias, float* __restrict__ out,
    int M, int N, int K)
{
    __shared__ __attribute__((aligned(16))) short As[64 * 32];
    __shared__ __attribute__((aligned(16))) short Bs[128 * 32];

    const int tid  = threadIdx.x;
    const int wave = tid >> 6, lane = tid & 63;
    const int quad = lane >> 4, lr = lane & 15;
    const int wm = wave >> 1, wn = wave & 1;
    const int m0 = blockIdx.y * 64, n0 = blockIdx.x * 128;

    f32x4 acc[2][4];
    const f32x4 zf = {0.f, 0.f, 0.f, 0.f};
#pragma unroll
    for (int mi = 0; mi < 2; mi++)
#pragma unroll
        for (int ni = 0; ni < 4; ni++) acc[mi][ni] = zf;

    for (int k0 = 0; k0 < K; k0 += 32) {
        __syncthreads();
        {   // A: 64x32 (4KB) = 1 gl16/thread, head-layout gather
            int row = tid >> 2, kc = (tid & 3) << 3;
            int rg = m0 + row, b = rg >> 11, t = rg & 2047;
            int c = k0 + kc, h = c >> 6, d = c & 63;
            gl16(A + ((((size_t)b * Hh + h) * Tt + t) * HD + d), &As[tid * 8]);
        }
#pragma unroll
        for (int i = 0; i < 2; i++) {   // B: 128x32 (8KB) = 2 gl16/thread
            int id = i * 256 + tid;
            int row = id >> 2, kc = (id & 3) << 3;
            gl16(Bt + (size_t)(n0 + row) * K + k0 + kc, &Bs[id * 8]);
        }
        __syncthreads();

        bf16x8 af[2], bf[4];
#pragma unroll
        for (int mi = 0; mi < 2; mi++)
            af[mi] = *(bf16x8*)&As[(wm * 32 + mi * 16 + lr) * 32 + quad * 8];
#pragma unroll
        for (int ni = 0; ni < 4; ni++)
            bf[ni] = *(bf16x8*)&Bs[(wn * 64 + ni * 16 + lr) * 32 + quad * 8];
#pragma unroll
        for (int mi = 0; mi < 2; mi++)
#pragma unroll
            for (int ni = 0; ni < 4; ni++)
                acc[mi][ni] = __builtin_amdgcn_mfma_f32_16x16x32_bf16(
                    af[mi], bf[ni], acc[mi][ni], 0, 0, 0);
    }

#pragma unroll
    for (int mi = 0; mi < 2; mi++)
#pragma unroll
        for (int ni = 0; ni < 4; ni++) {
            int c = n0 + wn * 64 + ni * 16 + lr;
            float bv = bias[c];
#pragma unroll
            for (int r = 0; r < 4; r++) {
                int rg = m0 + wm * 32 + mi * 16 + quad * 4 + r;
                out[(size_t)rg * N + c] = acc[mi][ni][r] + bv;
            }
        }
}

// ---------------------------------------------------------------------------
// FALLBACK GEMM (round-3 structure) — only if ws can't hold transposed weights
// ---------------------------------------------------------------------------
__global__ __launch_bounds__(256) void gemm_f32src(
    const void* __restrict__ Araw, const float* __restrict__ Bm,
    const float* __restrict__ bias, float* __restrict__ out,
    short* __restrict__ qw, short* __restrict__ kw, short* __restrict__ vTw,
    int M, int N, int K, int mode)
{
    __shared__ __attribute__((aligned(16))) short As[128 * 32];
    __shared__ __attribute__((aligned(16))) short Bs[128 * 32];

    const int tid  = threadIdx.x;
    const int wave = tid >> 6, lane = tid & 63;
    const int quad = lane >> 4, lr = lane & 15;
    const int wm = wave >> 1, wn = wave & 1;
    const int m0 = blockIdx.y * 128, n0 = blockIdx.x * 128;

    f32x4 acc[4][4];
    const f32x4 zf = {0.f, 0.f, 0.f, 0.f};
#pragma unroll
    for (int mi = 0; mi < 4; mi++)
#pragma unroll
        for (int ni = 0; ni < 4; ni++) acc[mi][ni] = zf;

    for (int k0 = 0; k0 < K; k0 += 32) {
        __syncthreads();
        if (mode == 1) {
            const float* Af = (const float*)Araw;
#pragma unroll
            for (int i = 0; i < 4; i++) {
                int id  = i * 256 + tid;
                int row = id >> 3;
                int kc  = (id & 7) << 2;
                float4 v = *(const float4*)(Af + (size_t)(m0 + row) * K + k0 + kc);
                short* d = &As[row * 32 + kc];
                d[0] = f2b(v.x); d[1] = f2b(v.y); d[2] = f2b(v.z); d[3] = f2b(v.w);
            }
        } else {
            const short* Ah = (const short*)Araw;
#pragma unroll
            for (int i = 0; i < 2; i++) {
                int id  = i * 256 + tid;
                int row = id >> 2;
                int kc  = (id & 3) << 3;
                int rg = m0 + row, b = rg >> 11, t = rg & 2047;
                int c = k0 + kc, h = c >> 6, d = c & 63;
                *(bf16x8*)&As[row * 32 + kc] =
                    *(const bf16x8*)(Ah + ((((size_t)b * Hh + h) * Tt + t) * HD + d));
            }
        }
#pragma unroll
        for (int i = 0; i < 4; i++) {
            int id = i * 256 + tid;
            int kr = id >> 5;
            int nc = (id & 31) << 2;
            float4 v = *(const float4*)(Bm + (size_t)(k0 + kr) * N + n0 + nc);
            Bs[(nc + 0) * 32 + kr] = f2b(v.x);
            Bs[(nc + 1) * 32 + kr] = f2b(v.y);
            Bs[(nc + 2) * 32 + kr] = f2b(v.z);
            Bs[(nc + 3) * 32 + kr] = f2b(v.w);
        }
        __syncthreads();

        bf16x8 af[4], bf[4];
#pragma unroll
        for (int mi = 0; mi < 4; mi++)
            af[mi] = *(bf16x8*)&As[(wm * 64 + mi * 16 + lr) * 32 + quad * 8];
#pragma unroll
        for (int ni = 0; ni < 4; ni++)
            bf[ni] = *(bf16x8*)&Bs[(wn * 64 + ni * 16 + lr) * 32 + quad * 8];
#pragma unroll
        for (int mi = 0; mi < 4; mi++)
#pragma unroll
            for (int ni = 0; ni < 4; ni++)
                acc[mi][ni] = __builtin_amdgcn_mfma_f32_16x16x32_bf16(
                    af[mi], bf[ni], acc[mi][ni], 0, 0, 0);
    }

#pragma unroll
    for (int mi = 0; mi < 4; mi++) {
#pragma unroll
        for (int ni = 0; ni < 4; ni++) {
            int c = n0 + wn * 64 + ni * 16 + lr;
            float bv = bias[c];
#pragma unroll
            for (int r = 0; r < 4; r++) {
                int rg = m0 + wm * 64 + mi * 16 + quad * 4 + r;
                float val = acc[mi][ni][r] + bv;
                if (mode == 1) {
                    int which = c >> 10, cc = c & 1023;
                    int h = cc >> 6, d = cc & 63;
                    int b = rg >> 11, t = rg & 2047;
                    size_t bh = (size_t)b * Hh + h;
                    if (which == 0)      qw[(bh * Tt + t) * HD + d] = f2b(val * QS);
                    else if (which == 1) kw[(bh * Tt + t) * HD + d] = f2b(val);
                    else                 vTw[(bh * HD + d) * Tt + t] = f2b(val);
                } else {
                    out[(size_t)rg * N + c] = val;
                }
            }
        }
    }
}

// ---------------------------------------------------------------------------
// Flash causal attention, v6 — transpose-free P + uniform work pairing.
//  - 32-row q-tiles (64 tiles); block handles the PAIR (p, 63-p): each wave's
//    two mt slots map to one 16-row group from each tile -> every block does
//    ~33 half-chunk units of compute. NO load imbalance, no drain.
//  - block = 128 threads (2 waves): grid 1024 = 4 blocks/CU, fine-grained
//    barriers (2 waves each), 8 waves/CU sustained.
//  - 64-key chunks double-buffered via swizzled gl16 (slot s of row holds
//    col-chunk s^(row&7)); fragment b128/b64 reads conflict-free.
//  - S^T = K·Q^T (C-layout == 16x16x16_1k B-layout); exp2 + v_perm pack
//    feeds P^T straight into O^T = V^T·P^T. No LDS for P.
//  - l: per-lane scalar accumulation; 2 shuffles at end.
//  - bh = blockIdx&31 pins each bh's blocks to one XCD (K/V L2-resident).
// ---------------------------------------------------------------------------
__global__ __launch_bounds__(128) void attn_kernel(
    short* __restrict__ qw, const short* __restrict__ kw,
    const short* __restrict__ vTw)
{
    __shared__ __attribute__((aligned(16))) short Ks[2][4096]; // 64key x 64d
    __shared__ __attribute__((aligned(16))) short Vs[2][4096]; // 64d x 64key

    const int bh = blockIdx.x & 31;
    const int p  = blockIdx.x >> 5;       // 0..31
    const int pB = 63 - p;
    const int tid = threadIdx.x;          // 0..127
    const int wave = tid >> 6, lane = tid & 63;
    const int quad = lane >> 4, lr = lane & 15;

    short* qp = qw + (size_t)bh * Tt * HD;
    const short* kp = kw + (size_t)bh * Tt * HD;
    const short* vp = vTw + (size_t)bh * HD * Tt;

    const int r0m[2] = { p * 32 + wave * 16, pB * 32 + wave * 16 };

    // staging geometry: id in [0,512), row=id>>3, slot=id&7 holds col-chunk
    // (id&7)^(row&7); 4 gl16 per thread per matrix
    int srow[4], scol[4];
#pragma unroll
    for (int i = 0; i < 4; i++) {
        int id = i * 128 + tid;
        srow[i] = id >> 3;
        scol[i] = ((id & 7) ^ (srow[i] & 7)) << 3;
    }

    // Q B-fragments (n=lr=q-row, k=quad*8+j=d), q pre-scaled by QS
    bf16x8 aq[2][2];
#pragma unroll
    for (int mt = 0; mt < 2; mt++)
#pragma unroll
        for (int h = 0; h < 2; h++)
            aq[mt][h] = *(const bf16x8*)(qp + (size_t)(r0m[mt] + lr) * HD
                                            + h * 32 + quad * 8);

    const f32x4 zf = {0.f, 0.f, 0.f, 0.f};
    f32x4 o[2][4];          // O^T accum: col=lr=q-row, row=quad*4+r=d
    float lacc[2] = {0.f, 0.f};
#pragma unroll
    for (int mt = 0; mt < 2; mt++)
#pragma unroll
        for (int nt = 0; nt < 4; nt++) o[mt][nt] = zf;

    // prologue: stage chunk 0 into buffer 0
#pragma unroll
    for (int i = 0; i < 4; i++) {
        gl16(kp + (size_t)srow[i] * HD + scol[i], &Ks[0][(i * 128 + tid) * 8]);
        gl16(vp + (size_t)srow[i] * Tt + scol[i], &Vs[0][(i * 128 + tid) * 8]);
    }

    const int clast = (pB * 32 + 31) >> 6;
    for (int c = 0; c <= clast; ++c) {
        const int j0 = c << 6;
        const int cur = c & 1;
        __syncthreads();   // buf[cur] loads landed; buf[cur^1] reads done
        if (c < clast) {   // prefetch next chunk, flies during compute
#pragma unroll
            for (int i = 0; i < 4; i++) {
                gl16(kp + (size_t)(j0 + 64 + srow[i]) * HD + scol[i],
                     &Ks[cur ^ 1][(i * 128 + tid) * 8]);
                gl16(vp + (size_t)srow[i] * Tt + (j0 + 64) + scol[i],
                     &Vs[cur ^ 1][(i * 128 + tid) * 8]);
            }
        }
        const short* Kc = &Ks[cur][0];
        const short* Vc = &Vs[cur][0];
#pragma unroll
        for (int kt = 0; kt < 4; kt++) {
            const int k16 = j0 + kt * 16;
            const bool act0 = k16 <= r0m[0] + 15;
            const bool act1 = k16 <= r0m[1] + 15;
            if (!act1 && !act0) break;   // strips monotone in kt
            // K A-fragments (m=key=kt*16+lr, k=d)
            int krow = (kt * 16 + lr) * 8;
            bf16x8 kb0 = *(const bf16x8*)&Kc[(krow + (quad ^ (lr & 7))) * 8];
            bf16x8 kb1 = *(const bf16x8*)&Kc[(krow + ((4 + quad) ^ (lr & 7))) * 8];
            // V A-fragments (m=d=nt*16+lr, k=key=kt*16+quad*4+j), b64 reads
            bf16x4 va[4];
#pragma unroll
            for (int nt = 0; nt < 4; nt++) {
                int vrow = (nt * 16 + lr) * 8;
                int slot = (kt * 2 + (quad >> 1)) ^ (lr & 7);
                va[nt] = *(const bf16x4*)&Vc[(vrow + slot) * 8 + (quad & 1) * 4];
            }
#pragma unroll
            for (int mt = 0; mt < 2; mt++) {
                if (!(mt ? act1 : act0)) continue;
                f32x4 s = __builtin_amdgcn_mfma_f32_16x16x32_bf16(
                    kb0, aq[mt][0], zf, 0, 0, 0);
                s = __builtin_amdgcn_mfma_f32_16x16x32_bf16(
                    kb1, aq[mt][1], s, 0, 0, 0);
                const bool needmask = (k16 + 15) > r0m[mt];
                unsigned u[4];
#pragma unroll
                for (int r = 0; r < 4; r++) {
                    float e = __builtin_amdgcn_exp2f(s[r]);
                    if (needmask && (k16 + quad * 4 + r) > (r0m[mt] + lr)) e = 0.f;
                    u[r] = __builtin_bit_cast(unsigned, e);
                    lacc[mt] += __builtin_bit_cast(float, u[r] & 0xFFFF0000u);
                }
                // pack truncated-bf16 pairs -> P^T B-fragment (2 VGPRs)
                u32x2 pu = { __builtin_amdgcn_perm(u[1], u[0], 0x07060302u),
                             __builtin_amdgcn_perm(u[3], u[2], 0x07060302u) };
                bf16x4 pt = __builtin_bit_cast(bf16x4, pu);
#pragma unroll
                for (int nt = 0; nt < 4; nt++)
                    o[mt][nt] = __builtin_amdgcn_mfma_f32_16x16x16bf16_1k(
                        va[nt], pt, o[mt][nt], 0, 0, 0);
            }
        }
    }

    // finish l: sum the 4 key-quarters (quads) per q-row
#pragma unroll
    for (int mt = 0; mt < 2; mt++) {
        lacc[mt] += __shfl_xor(lacc[mt], 16, 64);
        lacc[mt] += __shfl_xor(lacc[mt], 32, 64);
        lacc[mt] = 1.0f / lacc[mt];
    }

    // store: q-row = r0m[mt]+lr, d = nt*16+quad*4..+3  (b64 per (mt,nt))
#pragma unroll
    for (int mt = 0; mt < 2; mt++)
#pragma unroll
        for (int nt = 0; nt < 4; nt++) {
            bf16x4 ov;
#pragma unroll
            for (int r = 0; r < 4; r++) ov[r] = f2b(o[mt][nt][r] * lacc[mt]);
            *(bf16x4*)(qp + (size_t)(r0m[mt] + lr) * HD + nt * 16 + quad * 4) = ov;
        }
}

extern "C" void kernel_launch(void* const* d_in, const int* in_sizes, int n_in,
                              void* d_out, int out_size, void* d_ws, size_t ws_size,
                              hipStream_t stream) {
    const float* x      = (const float*)d_in[0];
    const float* w_attn = (const float*)d_in[1];
    const float* b_attn = (const float*)d_in[2];
    const float* w_proj = (const float*)d_in[3];
    const float* b_proj = (const float*)d_in[4];
    float* out = (float*)d_out;

    const size_t per = (size_t)Bb * Hh * Tt * HD;    // 4,194,304 elems (8 MB)
    short* qw  = (short*)d_ws;                        // later holds attn output
    short* kw  = qw + per;
    short* vTw = kw + per;
    const int M = Bb * Tt;                            // 4096

    const size_t need_fast = (3 * per + per + (size_t)3072 * 1024 + (size_t)1024 * 1024) * 2;

    if (ws_size >= need_fast) {
        short* xbf = vTw + per;
        short* wAT = xbf + per;
        short* wPT = wAT + (size_t)3072 * 1024;

        prep_kernel<<<dim3(3072), 256, 0, stream>>>(x, xbf, w_attn, wAT, w_proj, wPT);

        gemm_qkv<<<dim3(3 * Cc / 128, M / 128), 256, 0, stream>>>(
            xbf, wAT, b_attn, qw, kw, vTw, M, 3 * Cc, Cc);

        attn_kernel<<<dim3(1024), 128, 0, stream>>>(qw, kw, vTw);

        gemm_proj<<<dim3(Cc / 128, M / 64), 256, 0, stream>>>(
            qw, wPT, b_proj, out, M, Cc, Cc);
    } else {
        gemm_f32src<<<dim3(3 * Cc / 128, M / 128), 256, 0, stream>>>(
            x, w_attn, b_attn, nullptr, qw, kw, vTw, M, 3 * Cc, Cc, 1);

        attn_kernel<<<dim3(1024), 128, 0, stream>>>(qw, kw, vTw);

        gemm_f32src<<<dim3(Cc / 128, M / 128), 256, 0, stream>>>(
            qw, w_proj, b_proj, out, nullptr, nullptr, nullptr, M, Cc, Cc, 2);
    }
}

// Round 10
// 195.009 us; speedup vs baseline: 1.1027x; 1.1027x over previous
//
#include <hip/hip_runtime.h>
#include <hip/hip_bf16.h>

#define Bb 2
#define Tt 2048
#define Cc 1024
#define Hh 16
#define HD 64
// 1/sqrt(64) * log2(e), folded into q at QKV epilogue so attn exp2 needs no mul
#define QS 0.18033688f

typedef __attribute__((ext_vector_type(8))) short bf16x8;
typedef __attribute__((ext_vector_type(4))) short bf16x4;
typedef __attribute__((ext_vector_type(4))) float f32x4;
typedef __attribute__((ext_vector_type(2))) unsigned int u32x2;

__device__ inline short f2b(float f) {
    unsigned int u = __builtin_bit_cast(unsigned int, f);
    unsigned int r = (u + 0x7FFFu + ((u >> 16) & 1u)) >> 16;
    return (short)(unsigned short)r;
}

// async global->LDS, 16B per lane; dst must be wave-uniform base + lane*16
__device__ inline void gl16(const void* g, void* l) {
    __builtin_amdgcn_global_load_lds(
        (const __attribute__((address_space(1))) void*)g,
        (__attribute__((address_space(3))) void*)l, 16, 0, 0);
}

// ---------------------------------------------------------------------------
// Fused pre-pass (single launch):
//   blocks [0,2048):      x fp32 -> bf16
//   blocks [2048,2816):   w_attn [1024,3072] -> wAT [3072][1024] bf16
//   blocks [2816,3072):   w_proj [1024,1024] -> wPT [1024][1024] bf16
// ---------------------------------------------------------------------------
__global__ __launch_bounds__(256) void prep_kernel(
    const float* __restrict__ x, short* __restrict__ xbf,
    const float* __restrict__ wA, short* __restrict__ wAT,
    const float* __restrict__ wP, short* __restrict__ wPT)
{
    const int bx = blockIdx.x, tid = threadIdx.x;
    if (bx < 2048) {
        int i = (bx * 256 + tid) * 8;
        float4 a = *(const float4*)(x + i);
        float4 b = *(const float4*)(x + i + 4);
        bf16x8 v;
        v[0] = f2b(a.x); v[1] = f2b(a.y); v[2] = f2b(a.z); v[3] = f2b(a.w);
        v[4] = f2b(b.x); v[5] = f2b(b.y); v[6] = f2b(b.z); v[7] = f2b(b.w);
        *(bf16x8*)(xbf + i) = v;
        return;
    }
    const float* W; short* WT; int N, t;
    if (bx < 2816) { t = bx - 2048; W = wA; WT = wAT; N = 3072; }
    else           { t = bx - 2816; W = wP; WT = wPT; N = 1024; }
    const int K = 1024;
    int k0 = (t & 15) * 64, n0 = (t >> 4) * 64;
    int nl = tid & 63, kg = tid >> 6;
    int n = n0 + nl;
    short v[16];
#pragma unroll
    for (int i = 0; i < 16; i++)
        v[i] = f2b(W[(size_t)(k0 + kg * 16 + i) * N + n]);
    short* dst = WT + (size_t)n * K + k0 + kg * 16;
    *(bf16x8*)dst = *(bf16x8*)&v[0];
    *(bf16x8*)(dst + 8) = *(bf16x8*)&v[8];
}

// ---------------------------------------------------------------------------
// QKV GEMM: 128x128 tile, BK=32, DOUBLE-BUFFERED gl16 staging (1 barrier/iter,
// loads for iter i+1 fly during iter i's MFMAs). Phase-aware 4-slot XOR
// swizzle (slot p holds col-chunk p^((row>>1)&3)): staging dst is
// lane-contiguous (gl16-legal) and fragment b128 reads are conflict-free.
// Epilogue scatters q(*QS),k -> [B,H,T,HD]; v-tiles go through an LDS
// transpose (stride 136) and store contiguous 16B to vT [B,H,HD,T].
// NOTE: no pointer-array LDS aliases (addrspacecast static-init is illegal
// on gfx950) — buffer selection is done with integer offsets.
// ---------------------------------------------------------------------------
__global__ __launch_bounds__(256) void gemm_qkv(
    const short* __restrict__ A, const short* __restrict__ Bt,
    const float* __restrict__ bias,
    short* __restrict__ qw, short* __restrict__ kw, short* __restrict__ vTw,
    int M, int N, int K)
{
    // 17408 shorts = 34.8 KB: As dbuf [0,8192), Bs dbuf [8192,16384);
    // v-epilogue transpose reuses [0, 128*136) after a barrier.
    __shared__ __attribute__((aligned(16))) short SH[17408];

    const int tid  = threadIdx.x;
    const int wave = tid >> 6, lane = tid & 63;
    const int quad = lane >> 4, lr = lane & 15;
    const int wm = wave >> 1, wn = wave & 1;
    const int m0 = blockIdx.y * 128, n0 = blockIdx.x * 128;

    // staging geometry: id in [0,512), row=id>>2, slot=id&3 holds col-chunk
    // (id&3)^((row>>1)&3); 2 gl16 per thread per matrix per buffer
    int srow[2], scol[2];
#pragma unroll
    for (int i = 0; i < 2; i++) {
        int id = i * 256 + tid;
        srow[i] = id >> 2;
        scol[i] = ((id & 3) ^ ((srow[i] >> 1) & 3)) << 3;
    }
    const int pfrag = quad ^ ((lr >> 1) & 3);   // read-slot for fragment loads

    f32x4 acc[4][4];
    const f32x4 zf = {0.f, 0.f, 0.f, 0.f};
#pragma unroll
    for (int mi = 0; mi < 4; mi++)
#pragma unroll
        for (int ni = 0; ni < 4; ni++) acc[mi][ni] = zf;

    // prologue: stage k-tile 0 into buffer 0
#pragma unroll
    for (int i = 0; i < 2; i++) {
        gl16(A + (size_t)(m0 + srow[i]) * K + scol[i], &SH[(i * 256 + tid) * 8]);
        gl16(Bt + (size_t)(n0 + srow[i]) * K + scol[i], &SH[8192 + (i * 256 + tid) * 8]);
    }

    const int iters = K >> 5;
    for (int it = 0; it < iters; ++it) {
        const int co = (it & 1) * 4096;        // current buffer offset
        const int no = ((it & 1) ^ 1) * 4096;  // next buffer offset
        __syncthreads();   // buf[cur] loads landed; buf[cur^1] reads done
        if (it + 1 < iters) {
            const int k1 = (it + 1) << 5;
#pragma unroll
            for (int i = 0; i < 2; i++) {
                gl16(A + (size_t)(m0 + srow[i]) * K + k1 + scol[i],
                     &SH[no + (i * 256 + tid) * 8]);
                gl16(Bt + (size_t)(n0 + srow[i]) * K + k1 + scol[i],
                     &SH[8192 + no + (i * 256 + tid) * 8]);
            }
        }
        bf16x8 af[4], bf[4];
#pragma unroll
        for (int mi = 0; mi < 4; mi++) {
            int row = wm * 64 + mi * 16 + lr;
            af[mi] = *(bf16x8*)&SH[co + (row * 4 + pfrag) * 8];
        }
#pragma unroll
        for (int ni = 0; ni < 4; ni++) {
            int row = wn * 64 + ni * 16 + lr;
            bf[ni] = *(bf16x8*)&SH[8192 + co + (row * 4 + pfrag) * 8];
        }
#pragma unroll
        for (int mi = 0; mi < 4; mi++)
#pragma unroll
            for (int ni = 0; ni < 4; ni++)
                acc[mi][ni] = __builtin_amdgcn_mfma_f32_16x16x32_bf16(
                    af[mi], bf[ni], acc[mi][ni], 0, 0, 0);
    }

    if (n0 < 2048) {
        // q/k sections: scatter stores (32B segments per quad)
#pragma unroll
        for (int mi = 0; mi < 4; mi++) {
#pragma unroll
            for (int ni = 0; ni < 4; ni++) {
                int c = n0 + wn * 64 + ni * 16 + lr;
                float bv = bias[c];
#pragma unroll
                for (int r = 0; r < 4; r++) {
                    int rg = m0 + wm * 64 + mi * 16 + quad * 4 + r;
                    float val = acc[mi][ni][r] + bv;
                    int which = c >> 10, cc = c & 1023;
                    int h = cc >> 6, d = cc & 63;
                    int b = rg >> 11, t = rg & 2047;
                    size_t bh = (size_t)b * Hh + h;
                    if (which == 0) qw[(bh * Tt + t) * HD + d] = f2b(val * QS);
                    else            kw[(bh * Tt + t) * HD + d] = f2b(val);
                }
            }
        }
    } else {
        // v section: transpose through LDS, then contiguous 16B stores
        __syncthreads();   // all waves done with staging buffers
#pragma unroll
        for (int ni = 0; ni < 4; ni++) {
            int cl = wn * 64 + ni * 16 + lr;            // local col 0..127
            float bv = bias[n0 + cl];
#pragma unroll
            for (int mi = 0; mi < 4; mi++)
#pragma unroll
                for (int r = 0; r < 4; r++) {
                    int tl = wm * 64 + mi * 16 + quad * 4 + r;
                    SH[cl * 136 + tl] = f2b(acc[mi][ni][r] + bv);
                }
        }
        __syncthreads();
        const int rl = tid >> 1, half = tid & 1;
        const int cc = (n0 & 1023) + rl;                // 0..1023
        const int h = cc >> 6, d = cc & 63;
        const int b = m0 >> 11, tb = (m0 & 2047) + half * 64;
        short* dst = vTw + (((size_t)b * Hh + h) * HD + d) * Tt + tb;
        const short* src = &SH[rl * 136 + half * 64];
#pragma unroll
        for (int jj = 0; jj < 8; jj++)
            *(bf16x8*)(dst + jj * 8) = *(const bf16x8*)(src + jj * 8);
    }
}

// ---------------------------------------------------------------------------
// Proj GEMM: 64x128 tile, BK=32 double-buffered gl16 staging (same swizzle),
// A head-gather [B,H,T,HD], fp32 out + bias. 512 blocks = 2/CU.
// ---------------------------------------------------------------------------
__global__ __launch_bounds__(256) void gemm_proj(
    const short* __restrict__ A, const short* __restrict__ Bt,
    const float* __restrict__ bias, float* __restrict__ out,
    int M, int N, int K)
{
    // layout: A dbuf [0,2048)+[2048,4096); B dbuf [4096,8192)+[8192,12288)
    __shared__ __attribute__((aligned(16))) short SH[12288];  // 24 KB

    const int tid  = threadIdx.x;
    const int wave = tid >> 6, lane = tid & 63;
    const int quad = lane >> 4, lr = lane & 15;
    const int wm = wave >> 1, wn = wave & 1;
    const int m0 = blockIdx.y * 64, n0 = blockIdx.x * 128;

    // A staging: 256 chunk-slots (64 rows x 4), 1 gl16/thread
    const int arow = tid >> 2;
    const int acol = ((tid & 3) ^ ((arow >> 1) & 3)) << 3;
    // B staging: 512 slots, 2 gl16/thread
    int brow[2], bcol[2];
#pragma unroll
    for (int i = 0; i < 2; i++) {
        int id = i * 256 + tid;
        brow[i] = id >> 2;
        bcol[i] = ((id & 3) ^ ((brow[i] >> 1) & 3)) << 3;
    }
    const int pfrag = quad ^ ((lr >> 1) & 3);

    f32x4 acc[2][4];
    const f32x4 zf = {0.f, 0.f, 0.f, 0.f};
#pragma unroll
    for (int mi = 0; mi < 2; mi++)
#pragma unroll
        for (int ni = 0; ni < 4; ni++) acc[mi][ni] = zf;

    // A source address for a (row, col-chunk) in head layout
    auto asrc = [&](int row, int col) -> const short* {
        int rg = m0 + row, b = rg >> 11, t = rg & 2047;
        int h = col >> 6, d = col & 63;
        return A + ((((size_t)b * Hh + h) * Tt + t) * HD + d);
    };

    // prologue
    gl16(asrc(arow, acol), &SH[tid * 8]);
#pragma unroll
    for (int i = 0; i < 2; i++)
        gl16(Bt + (size_t)(n0 + brow[i]) * K + bcol[i],
             &SH[4096 + (i * 256 + tid) * 8]);

    const int iters = K >> 5;
    for (int it = 0; it < iters; ++it) {
        const int coA = (it & 1) * 2048, noA = ((it & 1) ^ 1) * 2048;
        const int coB = (it & 1) * 4096, noB = ((it & 1) ^ 1) * 4096;
        __syncthreads();
        if (it + 1 < iters) {
            const int k1 = (it + 1) << 5;
            gl16(asrc(arow, k1 + acol), &SH[noA + tid * 8]);
#pragma unroll
            for (int i = 0; i < 2; i++)
                gl16(Bt + (size_t)(n0 + brow[i]) * K + k1 + bcol[i],
                     &SH[4096 + noB + (i * 256 + tid) * 8]);
        }
        bf16x8 af[2], bf[4];
#pragma unroll
        for (int mi = 0; mi < 2; mi++) {
            int row = wm * 32 + mi * 16 + lr;
            af[mi] = *(bf16x8*)&SH[coA + (row * 4 + pfrag) * 8];
        }
#pragma unroll
        for (int ni = 0; ni < 4; ni++) {
            int row = wn * 64 + ni * 16 + lr;
            bf[ni] = *(bf16x8*)&SH[4096 + coB + (row * 4 + pfrag) * 8];
        }
#pragma unroll
        for (int mi = 0; mi < 2; mi++)
#pragma unroll
            for (int ni = 0; ni < 4; ni++)
                acc[mi][ni] = __builtin_amdgcn_mfma_f32_16x16x32_bf16(
                    af[mi], bf[ni], acc[mi][ni], 0, 0, 0);
    }

#pragma unroll
    for (int mi = 0; mi < 2; mi++)
#pragma unroll
        for (int ni = 0; ni < 4; ni++) {
            int c = n0 + wn * 64 + ni * 16 + lr;
            float bv = bias[c];
#pragma unroll
            for (int r = 0; r < 4; r++) {
                int rg = m0 + wm * 32 + mi * 16 + quad * 4 + r;
                out[(size_t)rg * N + c] = acc[mi][ni][r] + bv;
            }
        }
}

// ---------------------------------------------------------------------------
// FALLBACK GEMM (round-3 structure) — only if ws can't hold transposed weights
// ---------------------------------------------------------------------------
__global__ __launch_bounds__(256) void gemm_f32src(
    const void* __restrict__ Araw, const float* __restrict__ Bm,
    const float* __restrict__ bias, float* __restrict__ out,
    short* __restrict__ qw, short* __restrict__ kw, short* __restrict__ vTw,
    int M, int N, int K, int mode)
{
    __shared__ __attribute__((aligned(16))) short As[128 * 32];
    __shared__ __attribute__((aligned(16))) short Bs[128 * 32];

    const int tid  = threadIdx.x;
    const int wave = tid >> 6, lane = tid & 63;
    const int quad = lane >> 4, lr = lane & 15;
    const int wm = wave >> 1, wn = wave & 1;
    const int m0 = blockIdx.y * 128, n0 = blockIdx.x * 128;

    f32x4 acc[4][4];
    const f32x4 zf = {0.f, 0.f, 0.f, 0.f};
#pragma unroll
    for (int mi = 0; mi < 4; mi++)
#pragma unroll
        for (int ni = 0; ni < 4; ni++) acc[mi][ni] = zf;

    for (int k0 = 0; k0 < K; k0 += 32) {
        __syncthreads();
        if (mode == 1) {
            const float* Af = (const float*)Araw;
#pragma unroll
            for (int i = 0; i < 4; i++) {
                int id  = i * 256 + tid;
                int row = id >> 3;
                int kc  = (id & 7) << 2;
                float4 v = *(const float4*)(Af + (size_t)(m0 + row) * K + k0 + kc);
                short* d = &As[row * 32 + kc];
                d[0] = f2b(v.x); d[1] = f2b(v.y); d[2] = f2b(v.z); d[3] = f2b(v.w);
            }
        } else {
            const short* Ah = (const short*)Araw;
#pragma unroll
            for (int i = 0; i < 2; i++) {
                int id  = i * 256 + tid;
                int row = id >> 2;
                int kc  = (id & 3) << 3;
                int rg = m0 + row, b = rg >> 11, t = rg & 2047;
                int c = k0 + kc, h = c >> 6, d = c & 63;
                *(bf16x8*)&As[row * 32 + kc] =
                    *(const bf16x8*)(Ah + ((((size_t)b * Hh + h) * Tt + t) * HD + d));
            }
        }
#pragma unroll
        for (int i = 0; i < 4; i++) {
            int id = i * 256 + tid;
            int kr = id >> 5;
            int nc = (id & 31) << 2;
            float4 v = *(const float4*)(Bm + (size_t)(k0 + kr) * N + n0 + nc);
            Bs[(nc + 0) * 32 + kr] = f2b(v.x);
            Bs[(nc + 1) * 32 + kr] = f2b(v.y);
            Bs[(nc + 2) * 32 + kr] = f2b(v.z);
            Bs[(nc + 3) * 32 + kr] = f2b(v.w);
        }
        __syncthreads();

        bf16x8 af[4], bf[4];
#pragma unroll
        for (int mi = 0; mi < 4; mi++)
            af[mi] = *(bf16x8*)&As[(wm * 64 + mi * 16 + lr) * 32 + quad * 8];
#pragma unroll
        for (int ni = 0; ni < 4; ni++)
            bf[ni] = *(bf16x8*)&Bs[(wn * 64 + ni * 16 + lr) * 32 + quad * 8];
#pragma unroll
        for (int mi = 0; mi < 4; mi++)
#pragma unroll
            for (int ni = 0; ni < 4; ni++)
                acc[mi][ni] = __builtin_amdgcn_mfma_f32_16x16x32_bf16(
                    af[mi], bf[ni], acc[mi][ni], 0, 0, 0);
    }

#pragma unroll
    for (int mi = 0; mi < 4; mi++) {
#pragma unroll
        for (int ni = 0; ni < 4; ni++) {
            int c = n0 + wn * 64 + ni * 16 + lr;
            float bv = bias[c];
#pragma unroll
            for (int r = 0; r < 4; r++) {
                int rg = m0 + wm * 64 + mi * 16 + quad * 4 + r;
                float val = acc[mi][ni][r] + bv;
                if (mode == 1) {
                    int which = c >> 10, cc = c & 1023;
                    int h = cc >> 6, d = cc & 63;
                    int b = rg >> 11, t = rg & 2047;
                    size_t bh = (size_t)b * Hh + h;
                    if (which == 0)      qw[(bh * Tt + t) * HD + d] = f2b(val * QS);
                    else if (which == 1) kw[(bh * Tt + t) * HD + d] = f2b(val);
                    else                 vTw[(bh * HD + d) * Tt + t] = f2b(val);
                } else {
                    out[(size_t)rg * N + c] = val;
                }
            }
        }
    }
}

// ---------------------------------------------------------------------------
// Flash causal attention, v6 — transpose-free P + uniform work pairing.
// (unchanged from round 8)
// ---------------------------------------------------------------------------
__global__ __launch_bounds__(128) void attn_kernel(
    short* __restrict__ qw, const short* __restrict__ kw,
    const short* __restrict__ vTw)
{
    __shared__ __attribute__((aligned(16))) short Ks[2][4096]; // 64key x 64d
    __shared__ __attribute__((aligned(16))) short Vs[2][4096]; // 64d x 64key

    const int bh = blockIdx.x & 31;
    const int p  = blockIdx.x >> 5;       // 0..31
    const int pB = 63 - p;
    const int tid = threadIdx.x;          // 0..127
    const int wave = tid >> 6, lane = tid & 63;
    const int quad = lane >> 4, lr = lane & 15;

    short* qp = qw + (size_t)bh * Tt * HD;
    const short* kp = kw + (size_t)bh * Tt * HD;
    const short* vp = vTw + (size_t)bh * HD * Tt;

    const int r0m[2] = { p * 32 + wave * 16, pB * 32 + wave * 16 };

    int srow[4], scol[4];
#pragma unroll
    for (int i = 0; i < 4; i++) {
        int id = i * 128 + tid;
        srow[i] = id >> 3;
        scol[i] = ((id & 7) ^ (srow[i] & 7)) << 3;
    }

    bf16x8 aq[2][2];
#pragma unroll
    for (int mt = 0; mt < 2; mt++)
#pragma unroll
        for (int h = 0; h < 2; h++)
            aq[mt][h] = *(const bf16x8*)(qp + (size_t)(r0m[mt] + lr) * HD
                                            + h * 32 + quad * 8);

    const f32x4 zf = {0.f, 0.f, 0.f, 0.f};
    f32x4 o[2][4];
    float lacc[2] = {0.f, 0.f};
#pragma unroll
    for (int mt = 0; mt < 2; mt++)
#pragma unroll
        for (int nt = 0; nt < 4; nt++) o[mt][nt] = zf;

#pragma unroll
    for (int i = 0; i < 4; i++) {
        gl16(kp + (size_t)srow[i] * HD + scol[i], &Ks[0][(i * 128 + tid) * 8]);
        gl16(vp + (size_t)srow[i] * Tt + scol[i], &Vs[0][(i * 128 + tid) * 8]);
    }

    const int clast = (pB * 32 + 31) >> 6;
    for (int c = 0; c <= clast; ++c) {
        const int j0 = c << 6;
        const int cur = c & 1;
        __syncthreads();
        if (c < clast) {
#pragma unroll
            for (int i = 0; i < 4; i++) {
                gl16(kp + (size_t)(j0 + 64 + srow[i]) * HD + scol[i],
                     &Ks[cur ^ 1][(i * 128 + tid) * 8]);
                gl16(vp + (size_t)srow[i] * Tt + (j0 + 64) + scol[i],
                     &Vs[cur ^ 1][(i * 128 + tid) * 8]);
            }
        }
        const short* Kc = &Ks[cur][0];
        const short* Vc = &Vs[cur][0];
#pragma unroll
        for (int kt = 0; kt < 4; kt++) {
            const int k16 = j0 + kt * 16;
            const bool act0 = k16 <= r0m[0] + 15;
            const bool act1 = k16 <= r0m[1] + 15;
            if (!act1 && !act0) break;
            int krow = (kt * 16 + lr) * 8;
            bf16x8 kb0 = *(const bf16x8*)&Kc[(krow + (quad ^ (lr & 7))) * 8];
            bf16x8 kb1 = *(const bf16x8*)&Kc[(krow + ((4 + quad) ^ (lr & 7))) * 8];
            bf16x4 va[4];
#pragma unroll
            for (int nt = 0; nt < 4; nt++) {
                int vrow = (nt * 16 + lr) * 8;
                int slot = (kt * 2 + (quad >> 1)) ^ (lr & 7);
                va[nt] = *(const bf16x4*)&Vc[(vrow + slot) * 8 + (quad & 1) * 4];
            }
#pragma unroll
            for (int mt = 0; mt < 2; mt++) {
                if (!(mt ? act1 : act0)) continue;
                f32x4 s = __builtin_amdgcn_mfma_f32_16x16x32_bf16(
                    kb0, aq[mt][0], zf, 0, 0, 0);
                s = __builtin_amdgcn_mfma_f32_16x16x32_bf16(
                    kb1, aq[mt][1], s, 0, 0, 0);
                const bool needmask = (k16 + 15) > r0m[mt];
                unsigned u[4];
#pragma unroll
                for (int r = 0; r < 4; r++) {
                    float e = __builtin_amdgcn_exp2f(s[r]);
                    if (needmask && (k16 + quad * 4 + r) > (r0m[mt] + lr)) e = 0.f;
                    u[r] = __builtin_bit_cast(unsigned, e);
                    lacc[mt] += __builtin_bit_cast(float, u[r] & 0xFFFF0000u);
                }
                u32x2 pu = { __builtin_amdgcn_perm(u[1], u[0], 0x07060302u),
                             __builtin_amdgcn_perm(u[3], u[2], 0x07060302u) };
                bf16x4 pt = __builtin_bit_cast(bf16x4, pu);
#pragma unroll
                for (int nt = 0; nt < 4; nt++)
                    o[mt][nt] = __builtin_amdgcn_mfma_f32_16x16x16bf16_1k(
                        va[nt], pt, o[mt][nt], 0, 0, 0);
            }
        }
    }

#pragma unroll
    for (int mt = 0; mt < 2; mt++) {
        lacc[mt] += __shfl_xor(lacc[mt], 16, 64);
        lacc[mt] += __shfl_xor(lacc[mt], 32, 64);
        lacc[mt] = 1.0f / lacc[mt];
    }

#pragma unroll
    for (int mt = 0; mt < 2; mt++)
#pragma unroll
        for (int nt = 0; nt < 4; nt++) {
            bf16x4 ov;
#pragma unroll
            for (int r = 0; r < 4; r++) ov[r] = f2b(o[mt][nt][r] * lacc[mt]);
            *(bf16x4*)(qp + (size_t)(r0m[mt] + lr) * HD + nt * 16 + quad * 4) = ov;
        }
}

extern "C" void kernel_launch(void* const* d_in, const int* in_sizes, int n_in,
                              void* d_out, int out_size, void* d_ws, size_t ws_size,
                              hipStream_t stream) {
    const float* x      = (const float*)d_in[0];
    const float* w_attn = (const float*)d_in[1];
    const float* b_attn = (const float*)d_in[2];
    const float* w_proj = (const float*)d_in[3];
    const float* b_proj = (const float*)d_in[4];
    float* out = (float*)d_out;

    const size_t per = (size_t)Bb * Hh * Tt * HD;    // 4,194,304 elems (8 MB)
    short* qw  = (short*)d_ws;                        // later holds attn output
    short* kw  = qw + per;
    short* vTw = kw + per;
    const int M = Bb * Tt;                            // 4096

    const size_t need_fast = (3 * per + per + (size_t)3072 * 1024 + (size_t)1024 * 1024) * 2;

    if (ws_size >= need_fast) {
        short* xbf = vTw + per;
        short* wAT = xbf + per;
        short* wPT = wAT + (size_t)3072 * 1024;

        prep_kernel<<<dim3(3072), 256, 0, stream>>>(x, xbf, w_attn, wAT, w_proj, wPT);

        gemm_qkv<<<dim3(3 * Cc / 128, M / 128), 256, 0, stream>>>(
            xbf, wAT, b_attn, qw, kw, vTw, M, 3 * Cc, Cc);

        attn_kernel<<<dim3(1024), 128, 0, stream>>>(qw, kw, vTw);

        gemm_proj<<<dim3(Cc / 128, M / 64), 256, 0, stream>>>(
            qw, wPT, b_proj, out, M, Cc, Cc);
    } else {
        gemm_f32src<<<dim3(3 * Cc / 128, M / 128), 256, 0, stream>>>(
            x, w_attn, b_attn, nullptr, qw, kw, vTw, M, 3 * Cc, Cc, 1);

        attn_kernel<<<dim3(1024), 128, 0, stream>>>(qw, kw, vTw);

        gemm_f32src<<<dim3(Cc / 128, M / 128), 256, 0, stream>>>(
            qw, w_proj, b_proj, out, nullptr, nullptr, nullptr, M, Cc, Cc, 2);
    }
}

// Round 11
// 188.617 us; speedup vs baseline: 1.1400x; 1.0339x over previous
//
#include <hip/hip_runtime.h>
#include <hip/hip_bf16.h>

#define Bb 2
#define Tt 2048
#define Cc 1024
#define Hh 16
#define HD 64
// 1/sqrt(64) * log2(e), folded into q at QKV epilogue so attn exp2 needs no mul
#define QS 0.18033688f

typedef __attribute__((ext_vector_type(8))) short bf16x8;
typedef __attribute__((ext_vector_type(4))) short bf16x4;
typedef __attribute__((ext_vector_type(4))) float f32x4;
typedef __attribute__((ext_vector_type(2))) unsigned int u32x2;

__device__ inline short f2b(float f) {
    unsigned int u = __builtin_bit_cast(unsigned int, f);
    unsigned int r = (u + 0x7FFFu + ((u >> 16) & 1u)) >> 16;
    return (short)(unsigned short)r;
}

// async global->LDS, 16B per lane; dst must be wave-uniform base + lane*16
__device__ inline void gl16(const void* g, void* l) {
    __builtin_amdgcn_global_load_lds(
        (const __attribute__((address_space(1))) void*)g,
        (__attribute__((address_space(3))) void*)l, 16, 0, 0);
}

// ---------------------------------------------------------------------------
// Fused pre-pass (single launch):
//   blocks [0,2048):      x fp32 -> bf16
//   blocks [2048,2816):   w_attn [1024,3072] -> wAT [3072][1024] bf16
//   blocks [2816,3072):   w_proj [1024,1024] -> wPT [1024][1024] bf16
// ---------------------------------------------------------------------------
__global__ __launch_bounds__(256) void prep_kernel(
    const float* __restrict__ x, short* __restrict__ xbf,
    const float* __restrict__ wA, short* __restrict__ wAT,
    const float* __restrict__ wP, short* __restrict__ wPT)
{
    const int bx = blockIdx.x, tid = threadIdx.x;
    if (bx < 2048) {
        int i = (bx * 256 + tid) * 8;
        float4 a = *(const float4*)(x + i);
        float4 b = *(const float4*)(x + i + 4);
        bf16x8 v;
        v[0] = f2b(a.x); v[1] = f2b(a.y); v[2] = f2b(a.z); v[3] = f2b(a.w);
        v[4] = f2b(b.x); v[5] = f2b(b.y); v[6] = f2b(b.z); v[7] = f2b(b.w);
        *(bf16x8*)(xbf + i) = v;
        return;
    }
    const float* W; short* WT; int N, t;
    if (bx < 2816) { t = bx - 2048; W = wA; WT = wAT; N = 3072; }
    else           { t = bx - 2816; W = wP; WT = wPT; N = 1024; }
    const int K = 1024;
    int k0 = (t & 15) * 64, n0 = (t >> 4) * 64;
    int nl = tid & 63, kg = tid >> 6;
    int n = n0 + nl;
    short v[16];
#pragma unroll
    for (int i = 0; i < 16; i++)
        v[i] = f2b(W[(size_t)(k0 + kg * 16 + i) * N + n]);
    short* dst = WT + (size_t)n * K + k0 + kg * 16;
    *(bf16x8*)dst = *(bf16x8*)&v[0];
    *(bf16x8*)(dst + 8) = *(bf16x8*)&v[8];
}

// ---------------------------------------------------------------------------
// QKV GEMM: 128x128 tile, BK=32, double-buffered gl16 staging, phase-aware
// 4-slot XOR swizzle. Epilogue scatters q(*QS),k -> [B,H,T,HD]; v-tiles
// transpose through LDS (stride 136) to vT [B,H,HD,T]. (unchanged, round 10)
// ---------------------------------------------------------------------------
__global__ __launch_bounds__(256) void gemm_qkv(
    const short* __restrict__ A, const short* __restrict__ Bt,
    const float* __restrict__ bias,
    short* __restrict__ qw, short* __restrict__ kw, short* __restrict__ vTw,
    int M, int N, int K)
{
    __shared__ __attribute__((aligned(16))) short SH[17408];

    const int tid  = threadIdx.x;
    const int wave = tid >> 6, lane = tid & 63;
    const int quad = lane >> 4, lr = lane & 15;
    const int wm = wave >> 1, wn = wave & 1;
    const int m0 = blockIdx.y * 128, n0 = blockIdx.x * 128;

    int srow[2], scol[2];
#pragma unroll
    for (int i = 0; i < 2; i++) {
        int id = i * 256 + tid;
        srow[i] = id >> 2;
        scol[i] = ((id & 3) ^ ((srow[i] >> 1) & 3)) << 3;
    }
    const int pfrag = quad ^ ((lr >> 1) & 3);

    f32x4 acc[4][4];
    const f32x4 zf = {0.f, 0.f, 0.f, 0.f};
#pragma unroll
    for (int mi = 0; mi < 4; mi++)
#pragma unroll
        for (int ni = 0; ni < 4; ni++) acc[mi][ni] = zf;

#pragma unroll
    for (int i = 0; i < 2; i++) {
        gl16(A + (size_t)(m0 + srow[i]) * K + scol[i], &SH[(i * 256 + tid) * 8]);
        gl16(Bt + (size_t)(n0 + srow[i]) * K + scol[i], &SH[8192 + (i * 256 + tid) * 8]);
    }

    const int iters = K >> 5;
    for (int it = 0; it < iters; ++it) {
        const int co = (it & 1) * 4096;
        const int no = ((it & 1) ^ 1) * 4096;
        __syncthreads();
        if (it + 1 < iters) {
            const int k1 = (it + 1) << 5;
#pragma unroll
            for (int i = 0; i < 2; i++) {
                gl16(A + (size_t)(m0 + srow[i]) * K + k1 + scol[i],
                     &SH[no + (i * 256 + tid) * 8]);
                gl16(Bt + (size_t)(n0 + srow[i]) * K + k1 + scol[i],
                     &SH[8192 + no + (i * 256 + tid) * 8]);
            }
        }
        bf16x8 af[4], bf[4];
#pragma unroll
        for (int mi = 0; mi < 4; mi++) {
            int row = wm * 64 + mi * 16 + lr;
            af[mi] = *(bf16x8*)&SH[co + (row * 4 + pfrag) * 8];
        }
#pragma unroll
        for (int ni = 0; ni < 4; ni++) {
            int row = wn * 64 + ni * 16 + lr;
            bf[ni] = *(bf16x8*)&SH[8192 + co + (row * 4 + pfrag) * 8];
        }
#pragma unroll
        for (int mi = 0; mi < 4; mi++)
#pragma unroll
            for (int ni = 0; ni < 4; ni++)
                acc[mi][ni] = __builtin_amdgcn_mfma_f32_16x16x32_bf16(
                    af[mi], bf[ni], acc[mi][ni], 0, 0, 0);
    }

    if (n0 < 2048) {
#pragma unroll
        for (int mi = 0; mi < 4; mi++) {
#pragma unroll
            for (int ni = 0; ni < 4; ni++) {
                int c = n0 + wn * 64 + ni * 16 + lr;
                float bv = bias[c];
#pragma unroll
                for (int r = 0; r < 4; r++) {
                    int rg = m0 + wm * 64 + mi * 16 + quad * 4 + r;
                    float val = acc[mi][ni][r] + bv;
                    int which = c >> 10, cc = c & 1023;
                    int h = cc >> 6, d = cc & 63;
                    int b = rg >> 11, t = rg & 2047;
                    size_t bh = (size_t)b * Hh + h;
                    if (which == 0) qw[(bh * Tt + t) * HD + d] = f2b(val * QS);
                    else            kw[(bh * Tt + t) * HD + d] = f2b(val);
                }
            }
        }
    } else {
        __syncthreads();
#pragma unroll
        for (int ni = 0; ni < 4; ni++) {
            int cl = wn * 64 + ni * 16 + lr;
            float bv = bias[n0 + cl];
#pragma unroll
            for (int mi = 0; mi < 4; mi++)
#pragma unroll
                for (int r = 0; r < 4; r++) {
                    int tl = wm * 64 + mi * 16 + quad * 4 + r;
                    SH[cl * 136 + tl] = f2b(acc[mi][ni][r] + bv);
                }
        }
        __syncthreads();
        const int rl = tid >> 1, half = tid & 1;
        const int cc = (n0 & 1023) + rl;
        const int h = cc >> 6, d = cc & 63;
        const int b = m0 >> 11, tb = (m0 & 2047) + half * 64;
        short* dst = vTw + (((size_t)b * Hh + h) * HD + d) * Tt + tb;
        const short* src = &SH[rl * 136 + half * 64];
#pragma unroll
        for (int jj = 0; jj < 8; jj++)
            *(bf16x8*)(dst + jj * 8) = *(const bf16x8*)(src + jj * 8);
    }
}

// ---------------------------------------------------------------------------
// Proj GEMM: 64x128 tile, BK=32 dbuf gl16, head-gather A, fp32 out.
// (unchanged, round 10)
// ---------------------------------------------------------------------------
__global__ __launch_bounds__(256) void gemm_proj(
    const short* __restrict__ A, const short* __restrict__ Bt,
    const float* __restrict__ bias, float* __restrict__ out,
    int M, int N, int K)
{
    __shared__ __attribute__((aligned(16))) short SH[12288];

    const int tid  = threadIdx.x;
    const int wave = tid >> 6, lane = tid & 63;
    const int quad = lane >> 4, lr = lane & 15;
    const int wm = wave >> 1, wn = wave & 1;
    const int m0 = blockIdx.y * 64, n0 = blockIdx.x * 128;

    const int arow = tid >> 2;
    const int acol = ((tid & 3) ^ ((arow >> 1) & 3)) << 3;
    int brow[2], bcol[2];
#pragma unroll
    for (int i = 0; i < 2; i++) {
        int id = i * 256 + tid;
        brow[i] = id >> 2;
        bcol[i] = ((id & 3) ^ ((brow[i] >> 1) & 3)) << 3;
    }
    const int pfrag = quad ^ ((lr >> 1) & 3);

    f32x4 acc[2][4];
    const f32x4 zf = {0.f, 0.f, 0.f, 0.f};
#pragma unroll
    for (int mi = 0; mi < 2; mi++)
#pragma unroll
        for (int ni = 0; ni < 4; ni++) acc[mi][ni] = zf;

    auto asrc = [&](int row, int col) -> const short* {
        int rg = m0 + row, b = rg >> 11, t = rg & 2047;
        int h = col >> 6, d = col & 63;
        return A + ((((size_t)b * Hh + h) * Tt + t) * HD + d);
    };

    gl16(asrc(arow, acol), &SH[tid * 8]);
#pragma unroll
    for (int i = 0; i < 2; i++)
        gl16(Bt + (size_t)(n0 + brow[i]) * K + bcol[i],
             &SH[4096 + (i * 256 + tid) * 8]);

    const int iters = K >> 5;
    for (int it = 0; it < iters; ++it) {
        const int coA = (it & 1) * 2048, noA = ((it & 1) ^ 1) * 2048;
        const int coB = (it & 1) * 4096, noB = ((it & 1) ^ 1) * 4096;
        __syncthreads();
        if (it + 1 < iters) {
            const int k1 = (it + 1) << 5;
            gl16(asrc(arow, k1 + acol), &SH[noA + tid * 8]);
#pragma unroll
            for (int i = 0; i < 2; i++)
                gl16(Bt + (size_t)(n0 + brow[i]) * K + k1 + bcol[i],
                     &SH[4096 + noB + (i * 256 + tid) * 8]);
        }
        bf16x8 af[2], bf[4];
#pragma unroll
        for (int mi = 0; mi < 2; mi++) {
            int row = wm * 32 + mi * 16 + lr;
            af[mi] = *(bf16x8*)&SH[coA + (row * 4 + pfrag) * 8];
        }
#pragma unroll
        for (int ni = 0; ni < 4; ni++) {
            int row = wn * 64 + ni * 16 + lr;
            bf[ni] = *(bf16x8*)&SH[4096 + coB + (row * 4 + pfrag) * 8];
        }
#pragma unroll
        for (int mi = 0; mi < 2; mi++)
#pragma unroll
            for (int ni = 0; ni < 4; ni++)
                acc[mi][ni] = __builtin_amdgcn_mfma_f32_16x16x32_bf16(
                    af[mi], bf[ni], acc[mi][ni], 0, 0, 0);
    }

#pragma unroll
    for (int mi = 0; mi < 2; mi++)
#pragma unroll
        for (int ni = 0; ni < 4; ni++) {
            int c = n0 + wn * 64 + ni * 16 + lr;
            float bv = bias[c];
#pragma unroll
            for (int r = 0; r < 4; r++) {
                int rg = m0 + wm * 32 + mi * 16 + quad * 4 + r;
                out[(size_t)rg * N + c] = acc[mi][ni][r] + bv;
            }
        }
}

// ---------------------------------------------------------------------------
// FALLBACK GEMM (round-3 structure) — only if ws can't hold transposed weights
// ---------------------------------------------------------------------------
__global__ __launch_bounds__(256) void gemm_f32src(
    const void* __restrict__ Araw, const float* __restrict__ Bm,
    const float* __restrict__ bias, float* __restrict__ out,
    short* __restrict__ qw, short* __restrict__ kw, short* __restrict__ vTw,
    int M, int N, int K, int mode)
{
    __shared__ __attribute__((aligned(16))) short As[128 * 32];
    __shared__ __attribute__((aligned(16))) short Bs[128 * 32];

    const int tid  = threadIdx.x;
    const int wave = tid >> 6, lane = tid & 63;
    const int quad = lane >> 4, lr = lane & 15;
    const int wm = wave >> 1, wn = wave & 1;
    const int m0 = blockIdx.y * 128, n0 = blockIdx.x * 128;

    f32x4 acc[4][4];
    const f32x4 zf = {0.f, 0.f, 0.f, 0.f};
#pragma unroll
    for (int mi = 0; mi < 4; mi++)
#pragma unroll
        for (int ni = 0; ni < 4; ni++) acc[mi][ni] = zf;

    for (int k0 = 0; k0 < K; k0 += 32) {
        __syncthreads();
        if (mode == 1) {
            const float* Af = (const float*)Araw;
#pragma unroll
            for (int i = 0; i < 4; i++) {
                int id  = i * 256 + tid;
                int row = id >> 3;
                int kc  = (id & 7) << 2;
                float4 v = *(const float4*)(Af + (size_t)(m0 + row) * K + k0 + kc);
                short* d = &As[row * 32 + kc];
                d[0] = f2b(v.x); d[1] = f2b(v.y); d[2] = f2b(v.z); d[3] = f2b(v.w);
            }
        } else {
            const short* Ah = (const short*)Araw;
#pragma unroll
            for (int i = 0; i < 2; i++) {
                int id  = i * 256 + tid;
                int row = id >> 2;
                int kc  = (id & 3) << 3;
                int rg = m0 + row, b = rg >> 11, t = rg & 2047;
                int c = k0 + kc, h = c >> 6, d = c & 63;
                *(bf16x8*)&As[row * 32 + kc] =
                    *(const bf16x8*)(Ah + ((((size_t)b * Hh + h) * Tt + t) * HD + d));
            }
        }
#pragma unroll
        for (int i = 0; i < 4; i++) {
            int id = i * 256 + tid;
            int kr = id >> 5;
            int nc = (id & 31) << 2;
            float4 v = *(const float4*)(Bm + (size_t)(k0 + kr) * N + n0 + nc);
            Bs[(nc + 0) * 32 + kr] = f2b(v.x);
            Bs[(nc + 1) * 32 + kr] = f2b(v.y);
            Bs[(nc + 2) * 32 + kr] = f2b(v.z);
            Bs[(nc + 3) * 32 + kr] = f2b(v.w);
        }
        __syncthreads();

        bf16x8 af[4], bf[4];
#pragma unroll
        for (int mi = 0; mi < 4; mi++)
            af[mi] = *(bf16x8*)&As[(wm * 64 + mi * 16 + lr) * 32 + quad * 8];
#pragma unroll
        for (int ni = 0; ni < 4; ni++)
            bf[ni] = *(bf16x8*)&Bs[(wn * 64 + ni * 16 + lr) * 32 + quad * 8];
#pragma unroll
        for (int mi = 0; mi < 4; mi++)
#pragma unroll
            for (int ni = 0; ni < 4; ni++)
                acc[mi][ni] = __builtin_amdgcn_mfma_f32_16x16x32_bf16(
                    af[mi], bf[ni], acc[mi][ni], 0, 0, 0);
    }

#pragma unroll
    for (int mi = 0; mi < 4; mi++) {
#pragma unroll
        for (int ni = 0; ni < 4; ni++) {
            int c = n0 + wn * 64 + ni * 16 + lr;
            float bv = bias[c];
#pragma unroll
            for (int r = 0; r < 4; r++) {
                int rg = m0 + wm * 64 + mi * 16 + quad * 4 + r;
                float val = acc[mi][ni][r] + bv;
                if (mode == 1) {
                    int which = c >> 10, cc = c & 1023;
                    int h = cc >> 6, d = cc & 63;
                    int b = rg >> 11, t = rg & 2047;
                    size_t bh = (size_t)b * Hh + h;
                    if (which == 0)      qw[(bh * Tt + t) * HD + d] = f2b(val * QS);
                    else if (which == 1) kw[(bh * Tt + t) * HD + d] = f2b(val);
                    else                 vTw[(bh * HD + d) * Tt + t] = f2b(val);
                } else {
                    out[(size_t)rg * N + c] = val;
                }
            }
        }
    }
}

// ---------------------------------------------------------------------------
// Flash causal attention, v7 — 4-wave blocks own TWO pairs.
//  - 32-row tiles, pairs (p, 63-p). Block g in 0..15 owns pairs {2g, 2g+1}:
//    tiles {2g, 63-2g, 2g+1, 62-2g} — index sum constant -> uniform compute
//    across all 512 blocks. Waves 0,1 -> pair 2g; waves 2,3 -> pair 2g+1.
//  - 4 waves share each staged 64-key K/V chunk: L2->LDS traffic per unit
//    compute HALVED vs round-10 (2-wave blocks).
//  - fragment LDS offsets hoisted out of the chunk loop (chunk-invariant).
//  - causal mask as wave-uniform branch: interior strips skip cmp/cndmask.
//  - lacc uses raw e (truncation consistency dropped: rel err <= 2^-9).
//  - transpose-free P path, lane-resident l, in-place output (unchanged).
// ---------------------------------------------------------------------------
__global__ __launch_bounds__(256) void attn_kernel(
    short* __restrict__ qw, const short* __restrict__ kw,
    const short* __restrict__ vTw)
{
    __shared__ __attribute__((aligned(16))) short Ks[2][4096]; // 64key x 64d
    __shared__ __attribute__((aligned(16))) short Vs[2][4096]; // 64d x 64key

    const int bh = blockIdx.x & 31;
    const int g  = blockIdx.x >> 5;          // 0..15
    const int tid = threadIdx.x;             // 0..255
    const int wave = tid >> 6, lane = tid & 63;
    const int quad = lane >> 4, lr = lane & 15;

    const int pA = 2 * g + (wave >> 1);      // this wave's pair
    const int pB = 63 - pA;
    const int wh = (wave & 1) * 16;
    const int r0m[2] = { pA * 32 + wh, pB * 32 + wh };

    short* qp = qw + (size_t)bh * Tt * HD;
    const short* kp = kw + (size_t)bh * Tt * HD;
    const short* vp = vTw + (size_t)bh * HD * Tt;

    // staging geometry: 512 slots, id=i*256+tid, row=id>>3, slot=id&7 holds
    // col-chunk (id&7)^(row&7); 2 gl16 per thread per matrix
    int srow[2], scol[2];
#pragma unroll
    for (int i = 0; i < 2; i++) {
        int id = i * 256 + tid;
        srow[i] = id >> 3;
        scol[i] = ((id & 7) ^ (srow[i] & 7)) << 3;
    }

    // hoisted chunk-invariant LDS fragment offsets
    int kbo0[4], kbo1[4], vao[4][4];
#pragma unroll
    for (int kt = 0; kt < 4; kt++) {
        int krow = (kt * 16 + lr) * 8;
        kbo0[kt] = (krow + (quad ^ (lr & 7))) * 8;
        kbo1[kt] = (krow + ((4 + quad) ^ (lr & 7))) * 8;
#pragma unroll
        for (int nt = 0; nt < 4; nt++) {
            int vrow = (nt * 16 + lr) * 8;
            int slot = (kt * 2 + (quad >> 1)) ^ (lr & 7);
            vao[kt][nt] = (vrow + slot) * 8 + (quad & 1) * 4;
        }
    }

    // Q B-fragments (n=lr=q-row, k=quad*8+j=d), q pre-scaled by QS
    bf16x8 aq[2][2];
#pragma unroll
    for (int mt = 0; mt < 2; mt++)
#pragma unroll
        for (int h = 0; h < 2; h++)
            aq[mt][h] = *(const bf16x8*)(qp + (size_t)(r0m[mt] + lr) * HD
                                            + h * 32 + quad * 8);

    const f32x4 zf = {0.f, 0.f, 0.f, 0.f};
    f32x4 o[2][4];
    float lacc[2] = {0.f, 0.f};
#pragma unroll
    for (int mt = 0; mt < 2; mt++)
#pragma unroll
        for (int nt = 0; nt < 4; nt++) o[mt][nt] = zf;

    // prologue: stage chunk 0 into buffer 0
#pragma unroll
    for (int i = 0; i < 2; i++) {
        gl16(kp + (size_t)srow[i] * HD + scol[i], &Ks[0][(i * 256 + tid) * 8]);
        gl16(vp + (size_t)srow[i] * Tt + scol[i], &Vs[0][(i * 256 + tid) * 8]);
    }

    // block loop bound covers the heaviest tile in the block (63-2g)
    const int clast = ((63 - 2 * g) * 32 + 31) >> 6;
    for (int c = 0; c <= clast; ++c) {
        const int j0 = c << 6;
        const int cur = c & 1;
        __syncthreads();   // buf[cur] loads landed; buf[cur^1] reads done
        if (c < clast) {   // prefetch next chunk, flies during compute
#pragma unroll
            for (int i = 0; i < 2; i++) {
                gl16(kp + (size_t)(j0 + 64 + srow[i]) * HD + scol[i],
                     &Ks[cur ^ 1][(i * 256 + tid) * 8]);
                gl16(vp + (size_t)srow[i] * Tt + (j0 + 64) + scol[i],
                     &Vs[cur ^ 1][(i * 256 + tid) * 8]);
            }
        }
        const short* Kc = &Ks[cur][0];
        const short* Vc = &Vs[cur][0];
#pragma unroll
        for (int kt = 0; kt < 4; kt++) {
            const int k16 = j0 + kt * 16;
            const bool act0 = k16 <= r0m[0] + 15;
            const bool act1 = k16 <= r0m[1] + 15;
            if (!act1 && !act0) break;   // strips monotone in kt
            bf16x8 kb0 = *(const bf16x8*)&Kc[kbo0[kt]];
            bf16x8 kb1 = *(const bf16x8*)&Kc[kbo1[kt]];
            bf16x4 va[4];
#pragma unroll
            for (int nt = 0; nt < 4; nt++)
                va[nt] = *(const bf16x4*)&Vc[vao[kt][nt]];
#pragma unroll
            for (int mt = 0; mt < 2; mt++) {
                if (!(mt ? act1 : act0)) continue;
                f32x4 s = __builtin_amdgcn_mfma_f32_16x16x32_bf16(
                    kb0, aq[mt][0], zf, 0, 0, 0);
                s = __builtin_amdgcn_mfma_f32_16x16x32_bf16(
                    kb1, aq[mt][1], s, 0, 0, 0);
                unsigned u[4];
                if (k16 + 15 <= r0m[mt]) {      // interior: no mask (uniform)
#pragma unroll
                    for (int r = 0; r < 4; r++) {
                        float e = __builtin_amdgcn_exp2f(s[r]);
                        u[r] = __builtin_bit_cast(unsigned, e);
                        lacc[mt] += e;
                    }
                } else {                         // diagonal strip: mask
#pragma unroll
                    for (int r = 0; r < 4; r++) {
                        float e = __builtin_amdgcn_exp2f(s[r]);
                        if ((k16 + quad * 4 + r) > (r0m[mt] + lr)) e = 0.f;
                        u[r] = __builtin_bit_cast(unsigned, e);
                        lacc[mt] += e;
                    }
                }
                u32x2 pu = { __builtin_amdgcn_perm(u[1], u[0], 0x07060302u),
                             __builtin_amdgcn_perm(u[3], u[2], 0x07060302u) };
                bf16x4 pt = __builtin_bit_cast(bf16x4, pu);
#pragma unroll
                for (int nt = 0; nt < 4; nt++)
                    o[mt][nt] = __builtin_amdgcn_mfma_f32_16x16x16bf16_1k(
                        va[nt], pt, o[mt][nt], 0, 0, 0);
            }
        }
    }

    // finish l: sum the 4 key-quarters (quads) per q-row
#pragma unroll
    for (int mt = 0; mt < 2; mt++) {
        lacc[mt] += __shfl_xor(lacc[mt], 16, 64);
        lacc[mt] += __shfl_xor(lacc[mt], 32, 64);
        lacc[mt] = 1.0f / lacc[mt];
    }

    // store: q-row = r0m[mt]+lr, d = nt*16+quad*4..+3  (b64 per (mt,nt))
#pragma unroll
    for (int mt = 0; mt < 2; mt++)
#pragma unroll
        for (int nt = 0; nt < 4; nt++) {
            bf16x4 ov;
#pragma unroll
            for (int r = 0; r < 4; r++) ov[r] = f2b(o[mt][nt][r] * lacc[mt]);
            *(bf16x4*)(qp + (size_t)(r0m[mt] + lr) * HD + nt * 16 + quad * 4) = ov;
        }
}

extern "C" void kernel_launch(void* const* d_in, const int* in_sizes, int n_in,
                              void* d_out, int out_size, void* d_ws, size_t ws_size,
                              hipStream_t stream) {
    const float* x      = (const float*)d_in[0];
    const float* w_attn = (const float*)d_in[1];
    const float* b_attn = (const float*)d_in[2];
    const float* w_proj = (const float*)d_in[3];
    const float* b_proj = (const float*)d_in[4];
    float* out = (float*)d_out;

    const size_t per = (size_t)Bb * Hh * Tt * HD;    // 4,194,304 elems (8 MB)
    short* qw  = (short*)d_ws;                        // later holds attn output
    short* kw  = qw + per;
    short* vTw = kw + per;
    const int M = Bb * Tt;                            // 4096

    const size_t need_fast = (3 * per + per + (size_t)3072 * 1024 + (size_t)1024 * 1024) * 2;

    if (ws_size >= need_fast) {
        short* xbf = vTw + per;
        short* wAT = xbf + per;
        short* wPT = wAT + (size_t)3072 * 1024;

        prep_kernel<<<dim3(3072), 256, 0, stream>>>(x, xbf, w_attn, wAT, w_proj, wPT);

        gemm_qkv<<<dim3(3 * Cc / 128, M / 128), 256, 0, stream>>>(
            xbf, wAT, b_attn, qw, kw, vTw, M, 3 * Cc, Cc);

        attn_kernel<<<dim3(512), 256, 0, stream>>>(qw, kw, vTw);

        gemm_proj<<<dim3(Cc / 128, M / 64), 256, 0, stream>>>(
            qw, wPT, b_proj, out, M, Cc, Cc);
    } else {
        gemm_f32src<<<dim3(3 * Cc / 128, M / 128), 256, 0, stream>>>(
            x, w_attn, b_attn, nullptr, qw, kw, vTw, M, 3 * Cc, Cc, 1);

        attn_kernel<<<dim3(512), 256, 0, stream>>>(qw, kw, vTw);

        gemm_f32src<<<dim3(Cc / 128, M / 128), 256, 0, stream>>>(
            qw, w_proj, b_proj, out, nullptr, nullptr, nullptr, M, Cc, Cc, 2);
    }
}